// Round 14
// baseline (246.339 us; speedup 1.0000x reference)
//
#include <hip/hip_runtime.h>

// Inverse 3D DWT (DB4, periodization), (4,256,256,256) fp32.
// pass 1: axis-1 streaming transform, x -> ws (scalar, dense-row grid, NT loads;
//         measured ~6.1 TB/s, at roofline)
// pass 2: PERSISTENT per-(b,d1)-slice block (grid=1024), 256 threads, looping
//         16 d2-tiles with double-buffered LDS (2 x 22x264 = 46.4 KB):
//           syncthreads (vmcnt drained -> buf[cur] staged)
//           issue global_load_lds for tile k+1 -> buf[cur^1]   (async)
//           axis-2 on buf[cur] (1 thread/column, dead-slot in-place)
//           s_waitcnt lgkmcnt(0); s_barrier   <-- LDS-only drain: staged
//                                                 loads stay in flight
//           axis-3 on buf[cur] + float4 stores
//         Staging latency hides under compute; HBM streams continuously.
// Polyphase: y[2m]   = sum_j s[(m+j-3)&127]*a[j] + w[..]*c[j]
//            y[2m+1] = sum_j s[(m+j-3)&127]*b[j] + w[..]*d[j]
// a[j]=h[6-2j], b[j]=h[7-2j], c[j]=h[2j+1], d[j]=-h[2j].

typedef float f32x2 __attribute__((ext_vector_type(2)));

#define FILT_DECL(h)                                          \
  const float a0 = h[6], a1 = h[4], a2 = h[2], a3 = h[0];     \
  const float b0 = h[7], b1 = h[5], b2 = h[3], b3 = h[1];     \
  const float c0 = h[1], c1 = h[3], c2 = h[5], c3 = h[7];     \
  const float d0 = -h[0], d1 = -h[2], d2 = -h[4], d3 = -h[6];

#define Y0(s0,s1,s2,s3,w0,w1,w2,w3)                                        \
  fmaf(w3, c3, fmaf(w2, c2, fmaf(w1, c1, fmaf(w0, c0,                      \
  fmaf(s3, a3, fmaf(s2, a2, fmaf(s1, a1, s0 * a0)))))))
#define Y1(s0,s1,s2,s3,w0,w1,w2,w3)                                        \
  fmaf(w3, d3, fmaf(w2, d2, fmaf(w1, d1, fmaf(w0, d0,                      \
  fmaf(s3, b3, fmaf(s2, b2, fmaf(s1, b1, s0 * b0)))))))

// packed fma: acc.xy += splat(s) * k.xy   (lowers to v_pk_fma_f32)
#define PKFMA(s, k, acc) __builtin_elementwise_fma((f32x2){(s),(s)}, (k), (acc))

// global -> LDS direct DMA, 4 bytes per lane
__device__ __forceinline__ void gload_lds4(const float* g, float* l) {
  auto gp = reinterpret_cast<const __attribute__((address_space(1))) int*>(
      reinterpret_cast<uintptr_t>(g));
  auto lp = reinterpret_cast<__attribute__((address_space(3))) int*>(
      reinterpret_cast<uintptr_t>(l));
  __builtin_amdgcn_global_load_lds(gp, lp, 4, 0, 0);
}

// ---------------- pass 1: axis 1 (row stride 65536), scalar, in -> tmp ----
__global__ __launch_bounds__(256) void wav_axis1_s(const float* __restrict__ in,
                                                   float* __restrict__ tmp,
                                                   const float* __restrict__ h) {
  const int inner = blockIdx.x * 256 + threadIdx.x;
  const int m0 = blockIdx.y * 64;
  const size_t base = (size_t)blockIdx.z * (256u * 65536u) + (unsigned)inner;
  const float* __restrict__ ps = in + base;
  const float* __restrict__ pw = in + base + (size_t)128 * 65536;
  float* __restrict__ po = tmp + base;
  FILT_DECL(h)
  float s0 = __builtin_nontemporal_load(&ps[(size_t)((m0 - 3) & 127) * 65536]);
  float s1 = __builtin_nontemporal_load(&ps[(size_t)((m0 - 2) & 127) * 65536]);
  float s2 = __builtin_nontemporal_load(&ps[(size_t)((m0 - 1) & 127) * 65536]);
  float w0 = __builtin_nontemporal_load(&pw[(size_t)((m0 - 3) & 127) * 65536]);
  float w1 = __builtin_nontemporal_load(&pw[(size_t)((m0 - 2) & 127) * 65536]);
  float w2 = __builtin_nontemporal_load(&pw[(size_t)((m0 - 1) & 127) * 65536]);
  for (int m = m0; m < m0 + 64; ++m) {
    const float s3 = __builtin_nontemporal_load(&ps[(size_t)m * 65536]);
    const float w3 = __builtin_nontemporal_load(&pw[(size_t)m * 65536]);
    po[(size_t)(2 * m) * 65536] = Y0(s0, s1, s2, s3, w0, w1, w2, w3);
    po[(size_t)(2 * m + 1) * 65536] = Y1(s0, s1, s2, s3, w0, w1, w2, w3);
    s0 = s1; s1 = s2; s2 = s3;
    w0 = w1; w1 = w2; w2 = w3;
  }
}

// ---------------- pass 2: persistent per-slice, double-buffered -----------
// LDS rows 0..10 = s, 11..21 = w.
// cols: [s-halo 0..2 | s 3..130 | pad | w-halo 132..134 | w 135..262]
#define LSTR 264
__global__ __launch_bounds__(256) void wav_t23p(const float* __restrict__ tmp,
                                                float* __restrict__ out,
                                                const float* __restrict__ hg) {
  __shared__ __align__(16) float lb[2][22 * LSTR];   // 46.4 KB -> 3 blocks/CU
  const int t = threadIdx.x;
  const size_t slice = blockIdx.x;                   // b*256 + d1
  const float* __restrict__ src = tmp + slice * 65536;
  float* __restrict__ dstb = out + slice * 65536 + 16 * (t & 15);
  FILT_DECL(hg)
  const f32x2 AB0 = {a0, b0}, AB1 = {a1, b1}, AB2 = {a2, b2}, AB3 = {a3, b3};
  const f32x2 CD0 = {c0, d0}, CD1 = {c1, d1}, CD2 = {c2, d2}, CD3 = {c3, d3};
  const int phys = t + ((t < 128) ? 3 : 7);
  // transformed cols 125..127 / 253..255 duplicated into halo slots
  const int hcol = (t >= 125 && t < 128) ? (t - 125)
                 : ((t >= 253) ? (t - 121) : -1);
  const int r = t >> 4, m0 = (t & 15) * 8;
  const int prow = ((r & 1) ? (11 + (r >> 1)) : (r >> 1)) * LSTR;

  // prologue: stage tile 0 into buf 0 (c = t fixed, row index literal)
  {
    const int mb2 = -3;
#pragma unroll
    for (int kk = 0; kk < 11; ++kk) {
      const int g2 = (mb2 + kk) & 127;
      gload_lds4(src + (g2 << 8) + t, &lb[0][kk * LSTR + phys]);
      gload_lds4(src + ((128 + g2) << 8) + t, &lb[0][(11 + kk) * LSTR + phys]);
    }
  }

  for (int d2t = 0; d2t < 16; ++d2t) {
    const int cur = d2t & 1;
    __syncthreads();            // full drain: buf[cur] staged & prev reads done

    // issue async stage of tile d2t+1 into the other buffer (in flight
    // across the whole compute below; drained by next-iter __syncthreads)
    if (d2t < 15) {
      const int mb2 = 8 * (d2t + 1) - 3;
      float* bb = lb[cur ^ 1];
#pragma unroll
      for (int kk = 0; kk < 11; ++kk) {
        const int g2 = (mb2 + kk) & 127;
        gload_lds4(src + (g2 << 8) + t, &bb[kk * LSTR + phys]);
        gload_lds4(src + ((128 + g2) << 8) + t, &bb[(11 + kk) * LSTR + phys]);
      }
    }

    float* __restrict__ lbc = lb[cur];

    // axis-2: one thread per column (8 pairs). Dead-slot in place: pair q
    // writes y0->row q, y1->row 11+q. Column thread-owned -> no x-lane hazard.
    {
      float S[11], W[11];
#pragma unroll
      for (int i = 0; i < 11; ++i) S[i] = lbc[i * LSTR + phys];
#pragma unroll
      for (int i = 0; i < 11; ++i) W[i] = lbc[(11 + i) * LSTR + phys];
#pragma unroll
      for (int q = 0; q < 8; ++q) {
        f32x2 acc = (f32x2){S[q], S[q]} * AB0;
        acc = PKFMA(S[q+1], AB1, acc);
        acc = PKFMA(S[q+2], AB2, acc);
        acc = PKFMA(S[q+3], AB3, acc);
        acc = PKFMA(W[q],   CD0, acc);
        acc = PKFMA(W[q+1], CD1, acc);
        acc = PKFMA(W[q+2], CD2, acc);
        acc = PKFMA(W[q+3], CD3, acc);
        lbc[q * LSTR + phys] = acc.x;
        lbc[(11 + q) * LSTR + phys] = acc.y;
        if (hcol >= 0) {
          lbc[q * LSTR + hcol] = acc.x;
          lbc[(11 + q) * LSTR + hcol] = acc.y;
        }
      }
    }

    // mid barrier: LDS-only drain. Deliberately NOT __syncthreads() -- the
    // in-flight global_load_lds (next tile) must stay outstanding (vmcnt
    // untouched); axis-3 below depends only on LDS writes (lgkmcnt).
    asm volatile("s_waitcnt lgkmcnt(0)\n\ts_barrier" ::: "memory");

    // axis-3: row r (phys via prow), 8 pairs from m0; halo layout ->
    // contiguous aligned reads: S[i]=lbc[prow+m0+i], W[i]=lbc[prow+132+m0+i]
    float S[11], W[11];
    {
      const float4 sa = *reinterpret_cast<const float4*>(&lbc[prow + m0]);
      const float4 sb = *reinterpret_cast<const float4*>(&lbc[prow + m0 + 4]);
      const float2 sc = *reinterpret_cast<const float2*>(&lbc[prow + m0 + 8]);
      S[0]=sa.x; S[1]=sa.y; S[2]=sa.z; S[3]=sa.w;
      S[4]=sb.x; S[5]=sb.y; S[6]=sb.z; S[7]=sb.w;
      S[8]=sc.x; S[9]=sc.y; S[10]=lbc[prow + m0 + 10];
      const float4 wa = *reinterpret_cast<const float4*>(&lbc[prow + 132 + m0]);
      const float4 wb = *reinterpret_cast<const float4*>(&lbc[prow + 132 + m0 + 4]);
      const float2 wc = *reinterpret_cast<const float2*>(&lbc[prow + 132 + m0 + 8]);
      W[0]=wa.x; W[1]=wa.y; W[2]=wa.z; W[3]=wa.w;
      W[4]=wb.x; W[5]=wb.y; W[6]=wb.z; W[7]=wb.w;
      W[8]=wc.x; W[9]=wc.y; W[10]=lbc[prow + 132 + m0 + 10];
    }
    float* __restrict__ dst = dstb + (size_t)(16 * d2t + r) * 256;
#pragma unroll
    for (int g = 0; g < 4; ++g) {
      f32x2 eA = (f32x2){S[2*g], S[2*g]} * AB0;
      eA = PKFMA(S[2*g+1], AB1, eA);
      eA = PKFMA(S[2*g+2], AB2, eA);
      eA = PKFMA(S[2*g+3], AB3, eA);
      eA = PKFMA(W[2*g],   CD0, eA);
      eA = PKFMA(W[2*g+1], CD1, eA);
      eA = PKFMA(W[2*g+2], CD2, eA);
      eA = PKFMA(W[2*g+3], CD3, eA);
      f32x2 eB = (f32x2){S[2*g+1], S[2*g+1]} * AB0;
      eB = PKFMA(S[2*g+2], AB1, eB);
      eB = PKFMA(S[2*g+3], AB2, eB);
      eB = PKFMA(S[2*g+4], AB3, eB);
      eB = PKFMA(W[2*g+1], CD0, eB);
      eB = PKFMA(W[2*g+2], CD1, eB);
      eB = PKFMA(W[2*g+3], CD2, eB);
      eB = PKFMA(W[2*g+4], CD3, eB);
      *reinterpret_cast<float4*>(dst + 4 * g) = make_float4(eA.x, eA.y, eB.x, eB.y);
    }
  }
}

// ================= fallback 3-pass (verified round 2) =================
__global__ __launch_bounds__(256) void wav_axis1(const float* __restrict__ in,
                                                 float* __restrict__ out,
                                                 const float* __restrict__ h) {
  const int inner = blockIdx.x * 256 + threadIdx.x;
  const int m0 = blockIdx.y * 64;
  const size_t base = (size_t)blockIdx.z * (256u * 65536u) + (unsigned)inner;
  const float* __restrict__ ps = in + base;
  const float* __restrict__ pw = in + base + (size_t)128 * 65536;
  float* __restrict__ po = out + base;
  FILT_DECL(h)
  float s0 = ps[(size_t)((m0 - 3) & 127) * 65536];
  float s1 = ps[(size_t)((m0 - 2) & 127) * 65536];
  float s2 = ps[(size_t)((m0 - 1) & 127) * 65536];
  float w0 = pw[(size_t)((m0 - 3) & 127) * 65536];
  float w1 = pw[(size_t)((m0 - 2) & 127) * 65536];
  float w2 = pw[(size_t)((m0 - 1) & 127) * 65536];
  for (int m = m0; m < m0 + 64; ++m) {
    const float s3 = ps[(size_t)m * 65536];
    const float w3 = pw[(size_t)m * 65536];
    po[(size_t)(2 * m) * 65536] = Y0(s0, s1, s2, s3, w0, w1, w2, w3);
    po[(size_t)(2 * m + 1) * 65536] = Y1(s0, s1, s2, s3, w0, w1, w2, w3);
    s0 = s1; s1 = s2; s2 = s3;
    w0 = w1; w1 = w2; w2 = w3;
  }
}

__global__ __launch_bounds__(256) void wav_axis2(float* __restrict__ buf,
                                                 const float* __restrict__ h) {
  __shared__ float tile[256][32];
  const int t = threadIdx.x;
  const int c = t & 31;
  const int g = t >> 5;
  const size_t slice = (size_t)(blockIdx.x >> 3);
  const int col0 = (blockIdx.x & 7) * 32;
  float* __restrict__ p = buf + slice * 65536 + col0;
#pragma unroll
  for (int i = 0; i < 32; ++i) {
    const int rr = i * 8 + g;
    tile[rr][c] = p[rr * 256 + c];
  }
  __syncthreads();
  FILT_DECL(h)
  const int m0 = g * 16;
  float s0 = tile[(m0 - 3) & 127][c];
  float s1 = tile[(m0 - 2) & 127][c];
  float s2 = tile[(m0 - 1) & 127][c];
  float w0 = tile[128 + ((m0 - 3) & 127)][c];
  float w1 = tile[128 + ((m0 - 2) & 127)][c];
  float w2 = tile[128 + ((m0 - 1) & 127)][c];
#pragma unroll
  for (int m = m0; m < m0 + 16; ++m) {
    const float s3 = tile[m][c];
    const float w3 = tile[128 + m][c];
    p[(2 * m) * 256 + c] = Y0(s0, s1, s2, s3, w0, w1, w2, w3);
    p[(2 * m + 1) * 256 + c] = Y1(s0, s1, s2, s3, w0, w1, w2, w3);
    s0 = s1; s1 = s2; s2 = s3;
    w0 = w1; w1 = w2; w2 = w3;
  }
}

__global__ __launch_bounds__(256) void wav_axis3(float* __restrict__ buf,
                                                 const float* __restrict__ h) {
  __shared__ float tile[512];
  const int t = threadIdx.x;
  float* __restrict__ p = buf + (size_t)blockIdx.x * 512;
  tile[t] = p[t];
  tile[256 + t] = p[256 + t];
  __syncthreads();
  FILT_DECL(h)
  const int rr = t >> 7;
  const int m = t & 127;
  const float* __restrict__ line = tile + rr * 256;
  const float s0 = line[(m - 3) & 127];
  const float s1 = line[(m - 2) & 127];
  const float s2 = line[(m - 1) & 127];
  const float s3 = line[m];
  const float w0 = line[128 + ((m - 3) & 127)];
  const float w1 = line[128 + ((m - 2) & 127)];
  const float w2 = line[128 + ((m - 1) & 127)];
  const float w3 = line[128 + m];
  float2 y;
  y.x = Y0(s0, s1, s2, s3, w0, w1, w2, w3);
  y.y = Y1(s0, s1, s2, s3, w0, w1, w2, w3);
  *reinterpret_cast<float2*>(p + rr * 256 + 2 * m) = y;
}

extern "C" void kernel_launch(void* const* d_in, const int* in_sizes, int n_in,
                              void* d_out, int out_size, void* d_ws, size_t ws_size,
                              hipStream_t stream) {
  const float* x = (const float*)d_in[0];
  const float* h = (const float*)d_in[1];
  float* out = (float*)d_out;
  const size_t need = (size_t)4 * 256 * 256 * 256 * 4;   // 268 MB intermediate

  if (ws_size >= need) {
    float* tmp = (float*)d_ws;
    wav_axis1_s<<<dim3(256, 2, 4), 256, 0, stream>>>(x, tmp, h);
    wav_t23p<<<dim3(1024), 256, 0, stream>>>(tmp, out, h);
  } else {
    wav_axis1<<<dim3(256, 2, 4), 256, 0, stream>>>(x, out, h);
    wav_axis2<<<dim3(8192), 256, 0, stream>>>(out, h);
    wav_axis3<<<dim3(131072), 256, 0, stream>>>(out, h);
  }
}

// Round 15
// 232.696 us; speedup vs baseline: 1.0586x; 1.0586x over previous
//
#include <hip/hip_runtime.h>

// Inverse 3D DWT (DB4, periodization), (4,256,256,256) fp32.
// pass 1: axis-1 streaming transform, x -> ws (scalar sliding window, NT loads;
//         measured ~6.1 TB/s, at roofline)
// pass 2: axis-2 as a REGISTER sliding-window stream along d2 (pass-1 style:
//         2 coalesced 1KB row loads/step, no LDS on the operand path), each
//         step emits 2 transformed rows into an 8-row LDS buffer (halo'd,
//         stride 264); every 4 steps a short axis-3 phase consumes the 8 rows
//         with aligned b128 reads and stores 8 output rows. 2 blocks/slice,
//         grid 2048 = 8 blocks/CU = 32 waves (full occupancy), 8.25 KB LDS.
// Polyphase: y[2m]   = sum_j s[(m+j-3)&127]*a[j] + w[..]*c[j]
//            y[2m+1] = sum_j s[(m+j-3)&127]*b[j] + w[..]*d[j]
// a[j]=h[6-2j], b[j]=h[7-2j], c[j]=h[2j+1], d[j]=-h[2j].

typedef float f32x2 __attribute__((ext_vector_type(2)));

#define FILT_DECL(h)                                          \
  const float a0 = h[6], a1 = h[4], a2 = h[2], a3 = h[0];     \
  const float b0 = h[7], b1 = h[5], b2 = h[3], b3 = h[1];     \
  const float c0 = h[1], c1 = h[3], c2 = h[5], c3 = h[7];     \
  const float d0 = -h[0], d1 = -h[2], d2 = -h[4], d3 = -h[6];

#define Y0(s0,s1,s2,s3,w0,w1,w2,w3)                                        \
  fmaf(w3, c3, fmaf(w2, c2, fmaf(w1, c1, fmaf(w0, c0,                      \
  fmaf(s3, a3, fmaf(s2, a2, fmaf(s1, a1, s0 * a0)))))))
#define Y1(s0,s1,s2,s3,w0,w1,w2,w3)                                        \
  fmaf(w3, d3, fmaf(w2, d2, fmaf(w1, d1, fmaf(w0, d0,                      \
  fmaf(s3, b3, fmaf(s2, b2, fmaf(s1, b1, s0 * b0)))))))

// packed fma: acc.xy += splat(s) * k.xy   (lowers to v_pk_fma_f32)
#define PKFMA(s, k, acc) __builtin_elementwise_fma((f32x2){(s),(s)}, (k), (acc))

// ---------------- pass 1: axis 1 (row stride 65536), scalar, in -> tmp ----
__global__ __launch_bounds__(256) void wav_axis1_s(const float* __restrict__ in,
                                                   float* __restrict__ tmp,
                                                   const float* __restrict__ h) {
  const int inner = blockIdx.x * 256 + threadIdx.x;
  const int m0 = blockIdx.y * 64;
  const size_t base = (size_t)blockIdx.z * (256u * 65536u) + (unsigned)inner;
  const float* __restrict__ ps = in + base;
  const float* __restrict__ pw = in + base + (size_t)128 * 65536;
  float* __restrict__ po = tmp + base;
  FILT_DECL(h)
  float s0 = __builtin_nontemporal_load(&ps[(size_t)((m0 - 3) & 127) * 65536]);
  float s1 = __builtin_nontemporal_load(&ps[(size_t)((m0 - 2) & 127) * 65536]);
  float s2 = __builtin_nontemporal_load(&ps[(size_t)((m0 - 1) & 127) * 65536]);
  float w0 = __builtin_nontemporal_load(&pw[(size_t)((m0 - 3) & 127) * 65536]);
  float w1 = __builtin_nontemporal_load(&pw[(size_t)((m0 - 2) & 127) * 65536]);
  float w2 = __builtin_nontemporal_load(&pw[(size_t)((m0 - 1) & 127) * 65536]);
  for (int m = m0; m < m0 + 64; ++m) {
    const float s3 = __builtin_nontemporal_load(&ps[(size_t)m * 65536]);
    const float w3 = __builtin_nontemporal_load(&pw[(size_t)m * 65536]);
    po[(size_t)(2 * m) * 65536] = Y0(s0, s1, s2, s3, w0, w1, w2, w3);
    po[(size_t)(2 * m + 1) * 65536] = Y1(s0, s1, s2, s3, w0, w1, w2, w3);
    s0 = s1; s1 = s2; s2 = s3;
    w0 = w1; w1 = w2; w2 = w3;
  }
}

// ---------------- pass 2: register-streamed axis-2 + LDS axis-3 -----------
// Row layout (264 floats, 16B-aligned): [s-halo s125..127 : 0..2 |
// s0..127 : 3..130 | pad : 131 | w-halo w125..127 : 132..134 | w0..127 :
// 135..262].  phys(col t) = t + (t<128 ? 3 : 7).
#define RSTR 264
__global__ __launch_bounds__(256) void wav_t23r(const float* __restrict__ tmp,
                                                float* __restrict__ out,
                                                const float* __restrict__ hg) {
  __shared__ __align__(16) float rb[8 * RSTR];   // 8.25 KB
  const int t = threadIdx.x;
  const size_t slice = blockIdx.x >> 1;          // b*256 + d1
  const int m0 = (blockIdx.x & 1) << 6;          // d2-pair range [m0, m0+64)
  const float* __restrict__ ps = tmp + slice * 65536 + t;           // s rows
  const float* __restrict__ pw = tmp + slice * 65536 + 32768 + t;   // w rows
  float* __restrict__ outs = out + slice * 65536;
  FILT_DECL(hg)
  const f32x2 AB0 = {a0, b0}, AB1 = {a1, b1}, AB2 = {a2, b2}, AB3 = {a3, b3};
  const f32x2 CD0 = {c0, d0}, CD1 = {c1, d1}, CD2 = {c2, d2}, CD3 = {c3, d3};
  const int phys = t + ((t < 128) ? 3 : 7);
  const int hcol = (t >= 125 && t < 128) ? (t - 125)
                 : ((t >= 253) ? (t - 121) : -1);
  const int lr = t >> 5;                         // phase-B row 0..7
  const int p0 = (t & 31) << 2;                  // phase-B first pair

  // init sliding window (rows m0-3..m0-1, wrapped)
  float S0 = ps[((m0 - 3) & 127) << 8];
  float S1 = ps[((m0 - 2) & 127) << 8];
  float S2 = ps[((m0 - 1) & 127) << 8];
  float W0 = pw[((m0 - 3) & 127) << 8];
  float W1 = pw[((m0 - 2) & 127) << 8];
  float W2 = pw[((m0 - 1) & 127) << 8];

  for (int ss = 0; ss < 16; ++ss) {
    const int ms = m0 + 4 * ss;
    // ---- phase A: axis-2 in registers -> 8 transformed rows into LDS
#pragma unroll
    for (int q = 0; q < 4; ++q) {
      const float S3 = ps[(ms + q) << 8];        // ms+q <= 127: no wrap
      const float W3 = pw[(ms + q) << 8];
      f32x2 acc = (f32x2){S0, S0} * AB0;
      acc = PKFMA(S1, AB1, acc);
      acc = PKFMA(S2, AB2, acc);
      acc = PKFMA(S3, AB3, acc);
      acc = PKFMA(W0, CD0, acc);
      acc = PKFMA(W1, CD1, acc);
      acc = PKFMA(W2, CD2, acc);
      acc = PKFMA(W3, CD3, acc);
      rb[(2 * q) * RSTR + phys] = acc.x;         // y[2(ms+q)]
      rb[(2 * q + 1) * RSTR + phys] = acc.y;     // y[2(ms+q)+1]
      if (hcol >= 0) {
        rb[(2 * q) * RSTR + hcol] = acc.x;
        rb[(2 * q + 1) * RSTR + hcol] = acc.y;
      }
      S0 = S1; S1 = S2; S2 = S3;
      W0 = W1; W1 = W2; W2 = W3;
    }
    __syncthreads();

    // ---- phase B: axis-3 on the 8 rows (aligned vector reads) + store
    // S[i] = s[p0-3+i] at phys p0+i; W[i] = w[p0-3+i] at phys 132+p0+i.
    // (8th element of each pair of float4 loads is dead but in-bounds.)
    const int rbase = lr * RSTR;
    float S[8], W[8];
    {
      const float4 sa = *reinterpret_cast<const float4*>(&rb[rbase + p0]);
      const float4 sb = *reinterpret_cast<const float4*>(&rb[rbase + p0 + 4]);
      S[0]=sa.x; S[1]=sa.y; S[2]=sa.z; S[3]=sa.w;
      S[4]=sb.x; S[5]=sb.y; S[6]=sb.z; S[7]=sb.w;
      const float4 wa = *reinterpret_cast<const float4*>(&rb[rbase + 132 + p0]);
      const float4 wb = *reinterpret_cast<const float4*>(&rb[rbase + 132 + p0 + 4]);
      W[0]=wa.x; W[1]=wa.y; W[2]=wa.z; W[3]=wa.w;
      W[4]=wb.x; W[5]=wb.y; W[6]=wb.z; W[7]=wb.w;
    }
    float* __restrict__ dst = outs + (size_t)(2 * ms + lr) * 256 + 2 * p0;
#pragma unroll
    for (int g = 0; g < 2; ++g) {
      const int k = 2 * g;
      f32x2 eA = (f32x2){S[k], S[k]} * AB0;      // pair p0+k
      eA = PKFMA(S[k+1], AB1, eA);
      eA = PKFMA(S[k+2], AB2, eA);
      eA = PKFMA(S[k+3], AB3, eA);
      eA = PKFMA(W[k],   CD0, eA);
      eA = PKFMA(W[k+1], CD1, eA);
      eA = PKFMA(W[k+2], CD2, eA);
      eA = PKFMA(W[k+3], CD3, eA);
      f32x2 eB = (f32x2){S[k+1], S[k+1]} * AB0;  // pair p0+k+1
      eB = PKFMA(S[k+2], AB1, eB);
      eB = PKFMA(S[k+3], AB2, eB);
      eB = PKFMA(S[k+4], AB3, eB);
      eB = PKFMA(W[k+1], CD0, eB);
      eB = PKFMA(W[k+2], CD1, eB);
      eB = PKFMA(W[k+3], CD2, eB);
      eB = PKFMA(W[k+4], CD3, eB);
      *reinterpret_cast<float4*>(dst + 4 * g) = make_float4(eA.x, eA.y, eB.x, eB.y);
    }
    __syncthreads();
  }
}

// ================= fallback 3-pass (verified round 2) =================
__global__ __launch_bounds__(256) void wav_axis1(const float* __restrict__ in,
                                                 float* __restrict__ out,
                                                 const float* __restrict__ h) {
  const int inner = blockIdx.x * 256 + threadIdx.x;
  const int m0 = blockIdx.y * 64;
  const size_t base = (size_t)blockIdx.z * (256u * 65536u) + (unsigned)inner;
  const float* __restrict__ ps = in + base;
  const float* __restrict__ pw = in + base + (size_t)128 * 65536;
  float* __restrict__ po = out + base;
  FILT_DECL(h)
  float s0 = ps[(size_t)((m0 - 3) & 127) * 65536];
  float s1 = ps[(size_t)((m0 - 2) & 127) * 65536];
  float s2 = ps[(size_t)((m0 - 1) & 127) * 65536];
  float w0 = pw[(size_t)((m0 - 3) & 127) * 65536];
  float w1 = pw[(size_t)((m0 - 2) & 127) * 65536];
  float w2 = pw[(size_t)((m0 - 1) & 127) * 65536];
  for (int m = m0; m < m0 + 64; ++m) {
    const float s3 = ps[(size_t)m * 65536];
    const float w3 = pw[(size_t)m * 65536];
    po[(size_t)(2 * m) * 65536] = Y0(s0, s1, s2, s3, w0, w1, w2, w3);
    po[(size_t)(2 * m + 1) * 65536] = Y1(s0, s1, s2, s3, w0, w1, w2, w3);
    s0 = s1; s1 = s2; s2 = s3;
    w0 = w1; w1 = w2; w2 = w3;
  }
}

__global__ __launch_bounds__(256) void wav_axis2(float* __restrict__ buf,
                                                 const float* __restrict__ h) {
  __shared__ float tile[256][32];
  const int t = threadIdx.x;
  const int c = t & 31;
  const int g = t >> 5;
  const size_t slice = (size_t)(blockIdx.x >> 3);
  const int col0 = (blockIdx.x & 7) * 32;
  float* __restrict__ p = buf + slice * 65536 + col0;
#pragma unroll
  for (int i = 0; i < 32; ++i) {
    const int rr = i * 8 + g;
    tile[rr][c] = p[rr * 256 + c];
  }
  __syncthreads();
  FILT_DECL(h)
  const int m0 = g * 16;
  float s0 = tile[(m0 - 3) & 127][c];
  float s1 = tile[(m0 - 2) & 127][c];
  float s2 = tile[(m0 - 1) & 127][c];
  float w0 = tile[128 + ((m0 - 3) & 127)][c];
  float w1 = tile[128 + ((m0 - 2) & 127)][c];
  float w2 = tile[128 + ((m0 - 1) & 127)][c];
#pragma unroll
  for (int m = m0; m < m0 + 16; ++m) {
    const float s3 = tile[m][c];
    const float w3 = tile[128 + m][c];
    p[(2 * m) * 256 + c] = Y0(s0, s1, s2, s3, w0, w1, w2, w3);
    p[(2 * m + 1) * 256 + c] = Y1(s0, s1, s2, s3, w0, w1, w2, w3);
    s0 = s1; s1 = s2; s2 = s3;
    w0 = w1; w1 = w2; w2 = w3;
  }
}

__global__ __launch_bounds__(256) void wav_axis3(float* __restrict__ buf,
                                                 const float* __restrict__ h) {
  __shared__ float tile[512];
  const int t = threadIdx.x;
  float* __restrict__ p = buf + (size_t)blockIdx.x * 512;
  tile[t] = p[t];
  tile[256 + t] = p[256 + t];
  __syncthreads();
  FILT_DECL(h)
  const int rr = t >> 7;
  const int m = t & 127;
  const float* __restrict__ line = tile + rr * 256;
  const float s0 = line[(m - 3) & 127];
  const float s1 = line[(m - 2) & 127];
  const float s2 = line[(m - 1) & 127];
  const float s3 = line[m];
  const float w0 = line[128 + ((m - 3) & 127)];
  const float w1 = line[128 + ((m - 2) & 127)];
  const float w2 = line[128 + ((m - 1) & 127)];
  const float w3 = line[128 + m];
  float2 y;
  y.x = Y0(s0, s1, s2, s3, w0, w1, w2, w3);
  y.y = Y1(s0, s1, s2, s3, w0, w1, w2, w3);
  *reinterpret_cast<float2*>(p + rr * 256 + 2 * m) = y;
}

extern "C" void kernel_launch(void* const* d_in, const int* in_sizes, int n_in,
                              void* d_out, int out_size, void* d_ws, size_t ws_size,
                              hipStream_t stream) {
  const float* x = (const float*)d_in[0];
  const float* h = (const float*)d_in[1];
  float* out = (float*)d_out;
  const size_t need = (size_t)4 * 256 * 256 * 256 * 4;   // 268 MB intermediate

  if (ws_size >= need) {
    float* tmp = (float*)d_ws;
    wav_axis1_s<<<dim3(256, 2, 4), 256, 0, stream>>>(x, tmp, h);
    wav_t23r<<<dim3(2048), 256, 0, stream>>>(tmp, out, h);
  } else {
    wav_axis1<<<dim3(256, 2, 4), 256, 0, stream>>>(x, out, h);
    wav_axis2<<<dim3(8192), 256, 0, stream>>>(out, h);
    wav_axis3<<<dim3(131072), 256, 0, stream>>>(out, h);
  }
}

// Round 16
// 230.217 us; speedup vs baseline: 1.0700x; 1.0108x over previous
//
#include <hip/hip_runtime.h>

// Inverse 3D DWT (DB4, periodization), (4,256,256,256) fp32.
// pass 1: axis-1 streaming transform, x -> ws (scalar sliding window, NT loads;
//         measured ~6.1 TB/s, at roofline)
// pass 2: fused axis-2+axis-3, R13 tile (16 d2-rows x 256 d3, 22x264 LDS,
//         23.2 KB single buffer) made PERSISTENT over 8 tiles with a T14
//         async-STAGE split: per iter, issue next tile's 22 global loads into
//         REGISTERS early (they stay in flight across the compute phases and
//         asm barriers), consume current LDS tile (axis-2 in-place, axis-3 +
//         store), then ds_write the prefetched regs. Stage latency hides
//         under compute; single LDS buffer preserves multi-block residency.
// Polyphase: y[2m]   = sum_j s[(m+j-3)&127]*a[j] + w[..]*c[j]
//            y[2m+1] = sum_j s[(m+j-3)&127]*b[j] + w[..]*d[j]
// a[j]=h[6-2j], b[j]=h[7-2j], c[j]=h[2j+1], d[j]=-h[2j].

typedef float f32x2 __attribute__((ext_vector_type(2)));

#define FILT_DECL(h)                                          \
  const float a0 = h[6], a1 = h[4], a2 = h[2], a3 = h[0];     \
  const float b0 = h[7], b1 = h[5], b2 = h[3], b3 = h[1];     \
  const float c0 = h[1], c1 = h[3], c2 = h[5], c3 = h[7];     \
  const float d0 = -h[0], d1 = -h[2], d2 = -h[4], d3 = -h[6];

#define Y0(s0,s1,s2,s3,w0,w1,w2,w3)                                        \
  fmaf(w3, c3, fmaf(w2, c2, fmaf(w1, c1, fmaf(w0, c0,                      \
  fmaf(s3, a3, fmaf(s2, a2, fmaf(s1, a1, s0 * a0)))))))
#define Y1(s0,s1,s2,s3,w0,w1,w2,w3)                                        \
  fmaf(w3, d3, fmaf(w2, d2, fmaf(w1, d1, fmaf(w0, d0,                      \
  fmaf(s3, b3, fmaf(s2, b2, fmaf(s1, b1, s0 * b0)))))))

// packed fma: acc.xy += splat(s) * k.xy   (lowers to v_pk_fma_f32)
#define PKFMA(s, k, acc) __builtin_elementwise_fma((f32x2){(s),(s)}, (k), (acc))

// global -> LDS direct DMA, 4 bytes per lane (prologue staging only)
__device__ __forceinline__ void gload_lds4(const float* g, float* l) {
  auto gp = reinterpret_cast<const __attribute__((address_space(1))) int*>(
      reinterpret_cast<uintptr_t>(g));
  auto lp = reinterpret_cast<__attribute__((address_space(3))) int*>(
      reinterpret_cast<uintptr_t>(l));
  __builtin_amdgcn_global_load_lds(gp, lp, 4, 0, 0);
}

// ---------------- pass 1: axis 1 (row stride 65536), scalar, in -> tmp ----
__global__ __launch_bounds__(256) void wav_axis1_s(const float* __restrict__ in,
                                                   float* __restrict__ tmp,
                                                   const float* __restrict__ h) {
  const int inner = blockIdx.x * 256 + threadIdx.x;
  const int m0 = blockIdx.y * 64;
  const size_t base = (size_t)blockIdx.z * (256u * 65536u) + (unsigned)inner;
  const float* __restrict__ ps = in + base;
  const float* __restrict__ pw = in + base + (size_t)128 * 65536;
  float* __restrict__ po = tmp + base;
  FILT_DECL(h)
  float s0 = __builtin_nontemporal_load(&ps[(size_t)((m0 - 3) & 127) * 65536]);
  float s1 = __builtin_nontemporal_load(&ps[(size_t)((m0 - 2) & 127) * 65536]);
  float s2 = __builtin_nontemporal_load(&ps[(size_t)((m0 - 1) & 127) * 65536]);
  float w0 = __builtin_nontemporal_load(&pw[(size_t)((m0 - 3) & 127) * 65536]);
  float w1 = __builtin_nontemporal_load(&pw[(size_t)((m0 - 2) & 127) * 65536]);
  float w2 = __builtin_nontemporal_load(&pw[(size_t)((m0 - 1) & 127) * 65536]);
  for (int m = m0; m < m0 + 64; ++m) {
    const float s3 = __builtin_nontemporal_load(&ps[(size_t)m * 65536]);
    const float w3 = __builtin_nontemporal_load(&pw[(size_t)m * 65536]);
    po[(size_t)(2 * m) * 65536] = Y0(s0, s1, s2, s3, w0, w1, w2, w3);
    po[(size_t)(2 * m + 1) * 65536] = Y1(s0, s1, s2, s3, w0, w1, w2, w3);
    s0 = s1; s1 = s2; s2 = s3;
    w0 = w1; w1 = w2; w2 = w3;
  }
}

// ---------------- pass 2: persistent 8-tile loop, reg-prefetch ------------
// LDS rows 0..10 = s, 11..21 = w.
// cols: [s-halo 0..2 | s 3..130 | pad | w-halo 132..134 | w 135..262]
#define LSTR 264
__global__ __launch_bounds__(256, 4) void wav_t23f(const float* __restrict__ tmp,
                                                   float* __restrict__ out,
                                                   const float* __restrict__ hg) {
  __shared__ __align__(16) float lb[22 * LSTR];  // 23.2 KB, single buffer
  const int t = threadIdx.x;
  const size_t slice = blockIdx.x >> 1;          // b*256 + d1
  const int t0 = (blockIdx.x & 1) * 8;           // first of 8 d2-tiles
  const float* __restrict__ src = tmp + slice * 65536;
  float* __restrict__ outs = out + slice * 65536;
  FILT_DECL(hg)
  const f32x2 AB0 = {a0, b0}, AB1 = {a1, b1}, AB2 = {a2, b2}, AB3 = {a3, b3};
  const f32x2 CD0 = {c0, d0}, CD1 = {c1, d1}, CD2 = {c2, d2}, CD3 = {c3, d3};
  const int phys = t + ((t < 128) ? 3 : 7);
  // transformed cols 125..127 / 253..255 duplicated into halo slots
  const int hcol = (t >= 125 && t < 128) ? (t - 125)
                 : ((t >= 253) ? (t - 121) : -1);
  const int r = t >> 4, m0 = (t & 15) * 8;
  const int prow = ((r & 1) ? (11 + (r >> 1)) : (r >> 1)) * LSTR;

  // prologue: stage tile t0 via global_load_lds
  {
    const int mb2 = 8 * t0 - 3;
#pragma unroll
    for (int kk = 0; kk < 11; ++kk) {
      const int g2 = (mb2 + kk) & 127;
      gload_lds4(src + (g2 << 8) + t, &lb[kk * LSTR + phys]);
      gload_lds4(src + ((128 + g2) << 8) + t, &lb[(11 + kk) * LSTR + phys]);
    }
  }
  __syncthreads();

  for (int k = 0; k < 8; ++k) {
    // ---- issue next tile's loads into registers (in flight across the
    // compute below; the "memory"-clobbered asm barriers pin them here)
    float nx[22];
    if (k < 7) {
      const int mb2 = 8 * (t0 + k + 1) - 3;
#pragma unroll
      for (int kk = 0; kk < 11; ++kk) {
        const int g2 = (mb2 + kk) & 127;
        nx[kk]      = src[(g2 << 8) + t];
        nx[11 + kk] = src[((128 + g2) << 8) + t];
      }
    }

    // ---- axis-2: one thread per column (8 pairs), dead-slot in place:
    // pair q writes y0->row q, y1->row 11+q. Column thread-owned.
    {
      float S[11], W[11];
#pragma unroll
      for (int i = 0; i < 11; ++i) S[i] = lb[i * LSTR + phys];
#pragma unroll
      for (int i = 0; i < 11; ++i) W[i] = lb[(11 + i) * LSTR + phys];
#pragma unroll
      for (int q = 0; q < 8; ++q) {
        f32x2 acc = (f32x2){S[q], S[q]} * AB0;
        acc = PKFMA(S[q+1], AB1, acc);
        acc = PKFMA(S[q+2], AB2, acc);
        acc = PKFMA(S[q+3], AB3, acc);
        acc = PKFMA(W[q],   CD0, acc);
        acc = PKFMA(W[q+1], CD1, acc);
        acc = PKFMA(W[q+2], CD2, acc);
        acc = PKFMA(W[q+3], CD3, acc);
        lb[q * LSTR + phys] = acc.x;
        lb[(11 + q) * LSTR + phys] = acc.y;
        if (hcol >= 0) {
          lb[q * LSTR + hcol] = acc.x;
          lb[(11 + q) * LSTR + hcol] = acc.y;
        }
      }
    }
    // LDS-only drain + barrier: in-flight global loads stay outstanding
    asm volatile("s_waitcnt lgkmcnt(0)\n\ts_barrier" ::: "memory");

    // ---- axis-3: row r, 8 pairs from m0; halo layout -> aligned reads
    float S[11], W[11];
    {
      const float4 sa = *reinterpret_cast<const float4*>(&lb[prow + m0]);
      const float4 sb = *reinterpret_cast<const float4*>(&lb[prow + m0 + 4]);
      const float2 sc = *reinterpret_cast<const float2*>(&lb[prow + m0 + 8]);
      S[0]=sa.x; S[1]=sa.y; S[2]=sa.z; S[3]=sa.w;
      S[4]=sb.x; S[5]=sb.y; S[6]=sb.z; S[7]=sb.w;
      S[8]=sc.x; S[9]=sc.y; S[10]=lb[prow + m0 + 10];
      const float4 wa = *reinterpret_cast<const float4*>(&lb[prow + 132 + m0]);
      const float4 wb = *reinterpret_cast<const float4*>(&lb[prow + 132 + m0 + 4]);
      const float2 wc = *reinterpret_cast<const float2*>(&lb[prow + 132 + m0 + 8]);
      W[0]=wa.x; W[1]=wa.y; W[2]=wa.z; W[3]=wa.w;
      W[4]=wb.x; W[5]=wb.y; W[6]=wb.z; W[7]=wb.w;
      W[8]=wc.x; W[9]=wc.y; W[10]=lb[prow + 132 + m0 + 10];
    }
    float* __restrict__ dst = outs + (size_t)(16 * (t0 + k) + r) * 256 + 16 * (t & 15);
#pragma unroll
    for (int g = 0; g < 4; ++g) {
      f32x2 eA = (f32x2){S[2*g], S[2*g]} * AB0;
      eA = PKFMA(S[2*g+1], AB1, eA);
      eA = PKFMA(S[2*g+2], AB2, eA);
      eA = PKFMA(S[2*g+3], AB3, eA);
      eA = PKFMA(W[2*g],   CD0, eA);
      eA = PKFMA(W[2*g+1], CD1, eA);
      eA = PKFMA(W[2*g+2], CD2, eA);
      eA = PKFMA(W[2*g+3], CD3, eA);
      f32x2 eB = (f32x2){S[2*g+1], S[2*g+1]} * AB0;
      eB = PKFMA(S[2*g+2], AB1, eB);
      eB = PKFMA(S[2*g+3], AB2, eB);
      eB = PKFMA(S[2*g+4], AB3, eB);
      eB = PKFMA(W[2*g+1], CD0, eB);
      eB = PKFMA(W[2*g+2], CD1, eB);
      eB = PKFMA(W[2*g+3], CD2, eB);
      eB = PKFMA(W[2*g+4], CD3, eB);
      *reinterpret_cast<float4*>(dst + 4 * g) = make_float4(eA.x, eA.y, eB.x, eB.y);
    }

    if (k < 7) {
      // protect this iter's LDS reads (values already consumed into regs),
      // then publish the prefetched tile. Compiler inserts counted vmcnt
      // before each nx use.
      asm volatile("s_barrier" ::: "memory");
#pragma unroll
      for (int kk = 0; kk < 11; ++kk) {
        lb[kk * LSTR + phys]        = nx[kk];
        lb[(11 + kk) * LSTR + phys] = nx[11 + kk];
      }
      asm volatile("s_waitcnt lgkmcnt(0)\n\ts_barrier" ::: "memory");
    }
  }
}

// ================= fallback 3-pass (verified round 2) =================
__global__ __launch_bounds__(256) void wav_axis1(const float* __restrict__ in,
                                                 float* __restrict__ out,
                                                 const float* __restrict__ h) {
  const int inner = blockIdx.x * 256 + threadIdx.x;
  const int m0 = blockIdx.y * 64;
  const size_t base = (size_t)blockIdx.z * (256u * 65536u) + (unsigned)inner;
  const float* __restrict__ ps = in + base;
  const float* __restrict__ pw = in + base + (size_t)128 * 65536;
  float* __restrict__ po = out + base;
  FILT_DECL(h)
  float s0 = ps[(size_t)((m0 - 3) & 127) * 65536];
  float s1 = ps[(size_t)((m0 - 2) & 127) * 65536];
  float s2 = ps[(size_t)((m0 - 1) & 127) * 65536];
  float w0 = pw[(size_t)((m0 - 3) & 127) * 65536];
  float w1 = pw[(size_t)((m0 - 2) & 127) * 65536];
  float w2 = pw[(size_t)((m0 - 1) & 127) * 65536];
  for (int m = m0; m < m0 + 64; ++m) {
    const float s3 = ps[(size_t)m * 65536];
    const float w3 = pw[(size_t)m * 65536];
    po[(size_t)(2 * m) * 65536] = Y0(s0, s1, s2, s3, w0, w1, w2, w3);
    po[(size_t)(2 * m + 1) * 65536] = Y1(s0, s1, s2, s3, w0, w1, w2, w3);
    s0 = s1; s1 = s2; s2 = s3;
    w0 = w1; w1 = w2; w2 = w3;
  }
}

__global__ __launch_bounds__(256) void wav_axis2(float* __restrict__ buf,
                                                 const float* __restrict__ h) {
  __shared__ float tile[256][32];
  const int t = threadIdx.x;
  const int c = t & 31;
  const int g = t >> 5;
  const size_t slice = (size_t)(blockIdx.x >> 3);
  const int col0 = (blockIdx.x & 7) * 32;
  float* __restrict__ p = buf + slice * 65536 + col0;
#pragma unroll
  for (int i = 0; i < 32; ++i) {
    const int rr = i * 8 + g;
    tile[rr][c] = p[rr * 256 + c];
  }
  __syncthreads();
  FILT_DECL(h)
  const int m0 = g * 16;
  float s0 = tile[(m0 - 3) & 127][c];
  float s1 = tile[(m0 - 2) & 127][c];
  float s2 = tile[(m0 - 1) & 127][c];
  float w0 = tile[128 + ((m0 - 3) & 127)][c];
  float w1 = tile[128 + ((m0 - 2) & 127)][c];
  float w2 = tile[128 + ((m0 - 1) & 127)][c];
#pragma unroll
  for (int m = m0; m < m0 + 16; ++m) {
    const float s3 = tile[m][c];
    const float w3 = tile[128 + m][c];
    p[(2 * m) * 256 + c] = Y0(s0, s1, s2, s3, w0, w1, w2, w3);
    p[(2 * m + 1) * 256 + c] = Y1(s0, s1, s2, s3, w0, w1, w2, w3);
    s0 = s1; s1 = s2; s2 = s3;
    w0 = w1; w1 = w2; w2 = w3;
  }
}

__global__ __launch_bounds__(256) void wav_axis3(float* __restrict__ buf,
                                                 const float* __restrict__ h) {
  __shared__ float tile[512];
  const int t = threadIdx.x;
  float* __restrict__ p = buf + (size_t)blockIdx.x * 512;
  tile[t] = p[t];
  tile[256 + t] = p[256 + t];
  __syncthreads();
  FILT_DECL(h)
  const int rr = t >> 7;
  const int m = t & 127;
  const float* __restrict__ line = tile + rr * 256;
  const float s0 = line[(m - 3) & 127];
  const float s1 = line[(m - 2) & 127];
  const float s2 = line[(m - 1) & 127];
  const float s3 = line[m];
  const float w0 = line[128 + ((m - 3) & 127)];
  const float w1 = line[128 + ((m - 2) & 127)];
  const float w2 = line[128 + ((m - 1) & 127)];
  const float w3 = line[128 + m];
  float2 y;
  y.x = Y0(s0, s1, s2, s3, w0, w1, w2, w3);
  y.y = Y1(s0, s1, s2, s3, w0, w1, w2, w3);
  *reinterpret_cast<float2*>(p + rr * 256 + 2 * m) = y;
}

extern "C" void kernel_launch(void* const* d_in, const int* in_sizes, int n_in,
                              void* d_out, int out_size, void* d_ws, size_t ws_size,
                              hipStream_t stream) {
  const float* x = (const float*)d_in[0];
  const float* h = (const float*)d_in[1];
  float* out = (float*)d_out;
  const size_t need = (size_t)4 * 256 * 256 * 256 * 4;   // 268 MB intermediate

  if (ws_size >= need) {
    float* tmp = (float*)d_ws;
    wav_axis1_s<<<dim3(256, 2, 4), 256, 0, stream>>>(x, tmp, h);
    wav_t23f<<<dim3(2048), 256, 0, stream>>>(tmp, out, h);
  } else {
    wav_axis1<<<dim3(256, 2, 4), 256, 0, stream>>>(x, out, h);
    wav_axis2<<<dim3(8192), 256, 0, stream>>>(out, h);
    wav_axis3<<<dim3(131072), 256, 0, stream>>>(out, h);
  }
}

// Round 18
// 226.593 us; speedup vs baseline: 1.0871x; 1.0160x over previous
//
#include <hip/hip_runtime.h>

// Inverse 3D DWT (DB4, periodization), (4,256,256,256) fp32.
// NEW SPLIT (transforms commute):
//   pass A: axis-1 (register sliding window along d1, pass-1 shape) FUSED with
//           axis-3 (each 4-step phase bounces its 8 produced d1-rows through
//           an 8x264 halo'd LDS buffer and applies the d3 transform), x -> ws.
//   pass B: axis-2 ONLY — pure streaming sliding window along d2 (stride-256
//           rows, coalesced, no LDS, no barriers; the proven-roofline shape),
//           ws -> out.
// Polyphase: y[2m]   = sum_j s[(m+j-3)&127]*a[j] + w[..]*c[j]
//            y[2m+1] = sum_j s[(m+j-3)&127]*b[j] + w[..]*d[j]
// a[j]=h[6-2j], b[j]=h[7-2j], c[j]=h[2j+1], d[j]=-h[2j].
// NOTE: FILT_DECL owns a0..a3,b0..b3,c0..c3,d0..d3 — don't shadow.

typedef float f32x2 __attribute__((ext_vector_type(2)));

#define FILT_DECL(h)                                          \
  const float a0 = h[6], a1 = h[4], a2 = h[2], a3 = h[0];     \
  const float b0 = h[7], b1 = h[5], b2 = h[3], b3 = h[1];     \
  const float c0 = h[1], c1 = h[3], c2 = h[5], c3 = h[7];     \
  const float d0 = -h[0], d1 = -h[2], d2 = -h[4], d3 = -h[6];

#define Y0(s0,s1,s2,s3,w0,w1,w2,w3)                                        \
  fmaf(w3, c3, fmaf(w2, c2, fmaf(w1, c1, fmaf(w0, c0,                      \
  fmaf(s3, a3, fmaf(s2, a2, fmaf(s1, a1, s0 * a0)))))))
#define Y1(s0,s1,s2,s3,w0,w1,w2,w3)                                        \
  fmaf(w3, d3, fmaf(w2, d2, fmaf(w1, d1, fmaf(w0, d0,                      \
  fmaf(s3, b3, fmaf(s2, b2, fmaf(s1, b1, s0 * b0)))))))

// packed fma: acc.xy += splat(s) * k.xy   (lowers to v_pk_fma_f32)
#define PKFMA(s, k, acc) __builtin_elementwise_fma((f32x2){(s),(s)}, (k), (acc))

// ---------------- pass A: axis-1 + axis-3 fused, x -> tmp -----------------
// Grid (256,2,4): blockIdx.x = d2 row, .y = m-segment, .z = batch.
// Row layout (264 floats): [s-halo 0..2 | s 3..130 | pad | w-halo 132..134 |
// w 135..262]; phys(col t) = t + (t<128 ? 3 : 7).
#define RSTR 264
__global__ __launch_bounds__(256) void wav_a13(const float* __restrict__ in,
                                               float* __restrict__ tmp,
                                               const float* __restrict__ hg) {
  __shared__ __align__(16) float rb[8 * RSTR];   // 8.25 KB
  const int t = threadIdx.x;                     // d3
  const int col2 = blockIdx.x;                   // d2 row
  const int m0 = blockIdx.y * 64;
  const size_t bb = (size_t)blockIdx.z * 16777216;
  const float* __restrict__ ps = in + bb + col2 * 256 + t;        // s: d1 0..127
  const float* __restrict__ pw = ps + (size_t)128 * 65536;        // w: d1 128..255
  float* __restrict__ tout = tmp + bb + col2 * 256;
  FILT_DECL(hg)
  const f32x2 AB0 = {a0, b0}, AB1 = {a1, b1}, AB2 = {a2, b2}, AB3 = {a3, b3};
  const f32x2 CD0 = {c0, d0}, CD1 = {c1, d1}, CD2 = {c2, d2}, CD3 = {c3, d3};
  const int phys = t + ((t < 128) ? 3 : 7);
  const int hcol = (t >= 125 && t < 128) ? (t - 125)
                 : ((t >= 253) ? (t - 121) : -1);
  const int lr = t >> 5;                         // phase-B row 0..7
  const int p0 = (t & 31) << 2;                  // phase-B first pair

  // init sliding window (d1 rows m0-3..m0-1, wrapped)
  float S0 = __builtin_nontemporal_load(&ps[(size_t)((m0 - 3) & 127) * 65536]);
  float S1 = __builtin_nontemporal_load(&ps[(size_t)((m0 - 2) & 127) * 65536]);
  float S2 = __builtin_nontemporal_load(&ps[(size_t)((m0 - 1) & 127) * 65536]);
  float W0 = __builtin_nontemporal_load(&pw[(size_t)((m0 - 3) & 127) * 65536]);
  float W1 = __builtin_nontemporal_load(&pw[(size_t)((m0 - 2) & 127) * 65536]);
  float W2 = __builtin_nontemporal_load(&pw[(size_t)((m0 - 1) & 127) * 65536]);

  for (int ss = 0; ss < 16; ++ss) {
    const int ms = m0 + 4 * ss;
    // ---- phase A: axis-1 in registers -> 8 d1-rows into LDS (halo'd)
#pragma unroll
    for (int q = 0; q < 4; ++q) {
      const float S3 = __builtin_nontemporal_load(&ps[(size_t)(ms + q) * 65536]);
      const float W3 = __builtin_nontemporal_load(&pw[(size_t)(ms + q) * 65536]);
      f32x2 acc = (f32x2){S0, S0} * AB0;
      acc = PKFMA(S1, AB1, acc);
      acc = PKFMA(S2, AB2, acc);
      acc = PKFMA(S3, AB3, acc);
      acc = PKFMA(W0, CD0, acc);
      acc = PKFMA(W1, CD1, acc);
      acc = PKFMA(W2, CD2, acc);
      acc = PKFMA(W3, CD3, acc);
      rb[(2 * q) * RSTR + phys] = acc.x;         // d1out = 2(ms+q)
      rb[(2 * q + 1) * RSTR + phys] = acc.y;     // d1out = 2(ms+q)+1
      if (hcol >= 0) {
        rb[(2 * q) * RSTR + hcol] = acc.x;
        rb[(2 * q + 1) * RSTR + hcol] = acc.y;
      }
      S0 = S1; S1 = S2; S2 = S3;
      W0 = W1; W1 = W2; W2 = W3;
    }
    __syncthreads();

    // ---- phase B: axis-3 within each row (aligned vector reads) + store.
    // S[i] = s[p0-3+i] at phys p0+i; W[i] = w[p0-3+i] at phys 132+p0+i.
    const int rbase = lr * RSTR;
    float S[8], W[8];
    {
      const float4 sa = *reinterpret_cast<const float4*>(&rb[rbase + p0]);
      const float4 sb = *reinterpret_cast<const float4*>(&rb[rbase + p0 + 4]);
      S[0]=sa.x; S[1]=sa.y; S[2]=sa.z; S[3]=sa.w;
      S[4]=sb.x; S[5]=sb.y; S[6]=sb.z; S[7]=sb.w;
      const float4 wa = *reinterpret_cast<const float4*>(&rb[rbase + 132 + p0]);
      const float4 wb = *reinterpret_cast<const float4*>(&rb[rbase + 132 + p0 + 4]);
      W[0]=wa.x; W[1]=wa.y; W[2]=wa.z; W[3]=wa.w;
      W[4]=wb.x; W[5]=wb.y; W[6]=wb.z; W[7]=wb.w;
    }
    float* __restrict__ dst = tout + (size_t)(2 * ms + lr) * 65536 + 2 * p0;
#pragma unroll
    for (int g = 0; g < 2; ++g) {
      const int k = 2 * g;
      f32x2 eA = (f32x2){S[k], S[k]} * AB0;      // pair p0+k
      eA = PKFMA(S[k+1], AB1, eA);
      eA = PKFMA(S[k+2], AB2, eA);
      eA = PKFMA(S[k+3], AB3, eA);
      eA = PKFMA(W[k],   CD0, eA);
      eA = PKFMA(W[k+1], CD1, eA);
      eA = PKFMA(W[k+2], CD2, eA);
      eA = PKFMA(W[k+3], CD3, eA);
      f32x2 eB = (f32x2){S[k+1], S[k+1]} * AB0;  // pair p0+k+1
      eB = PKFMA(S[k+2], AB1, eB);
      eB = PKFMA(S[k+3], AB2, eB);
      eB = PKFMA(S[k+4], AB3, eB);
      eB = PKFMA(W[k+1], CD0, eB);
      eB = PKFMA(W[k+2], CD1, eB);
      eB = PKFMA(W[k+3], CD2, eB);
      eB = PKFMA(W[k+4], CD3, eB);
      *reinterpret_cast<float4*>(dst + 4 * g) = make_float4(eA.x, eA.y, eB.x, eB.y);
    }
    __syncthreads();
  }
}

// ---------------- pass B: axis-2 only, pure stream, tmp -> out ------------
// Grid (1024, 2): blockIdx.x = slice (b*256+d1), .y = m-segment.
// Sliding window along d2 (row stride 256 floats); no LDS, no barriers.
__global__ __launch_bounds__(256) void wav_b2(const float* __restrict__ tmp,
                                              float* __restrict__ out,
                                              const float* __restrict__ h) {
  const int t = threadIdx.x;                     // d3
  const int m0 = blockIdx.y * 64;
  const size_t slice = blockIdx.x;
  const float* __restrict__ ps = tmp + slice * 65536 + t;   // s: d2 0..127
  const float* __restrict__ pw = ps + 32768;                // w: d2 128..255
  float* __restrict__ po = out + slice * 65536 + t;
  FILT_DECL(h)
  float s0 = __builtin_nontemporal_load(&ps[((m0 - 3) & 127) * 256]);
  float s1 = __builtin_nontemporal_load(&ps[((m0 - 2) & 127) * 256]);
  float s2 = __builtin_nontemporal_load(&ps[((m0 - 1) & 127) * 256]);
  float w0 = __builtin_nontemporal_load(&pw[((m0 - 3) & 127) * 256]);
  float w1 = __builtin_nontemporal_load(&pw[((m0 - 2) & 127) * 256]);
  float w2 = __builtin_nontemporal_load(&pw[((m0 - 1) & 127) * 256]);
  for (int m = m0; m < m0 + 64; ++m) {
    const float s3 = __builtin_nontemporal_load(&ps[m * 256]);
    const float w3 = __builtin_nontemporal_load(&pw[m * 256]);
    po[(2 * m) * 256] = Y0(s0, s1, s2, s3, w0, w1, w2, w3);
    po[(2 * m + 1) * 256] = Y1(s0, s1, s2, s3, w0, w1, w2, w3);
    s0 = s1; s1 = s2; s2 = s3;
    w0 = w1; w1 = w2; w2 = w3;
  }
}

// ================= fallback 3-pass (verified round 2) =================
__global__ __launch_bounds__(256) void wav_axis1(const float* __restrict__ in,
                                                 float* __restrict__ out,
                                                 const float* __restrict__ h) {
  const int inner = blockIdx.x * 256 + threadIdx.x;
  const int m0 = blockIdx.y * 64;
  const size_t base = (size_t)blockIdx.z * (256u * 65536u) + (unsigned)inner;
  const float* __restrict__ ps = in + base;
  const float* __restrict__ pw = in + base + (size_t)128 * 65536;
  float* __restrict__ po = out + base;
  FILT_DECL(h)
  float s0 = ps[(size_t)((m0 - 3) & 127) * 65536];
  float s1 = ps[(size_t)((m0 - 2) & 127) * 65536];
  float s2 = ps[(size_t)((m0 - 1) & 127) * 65536];
  float w0 = pw[(size_t)((m0 - 3) & 127) * 65536];
  float w1 = pw[(size_t)((m0 - 2) & 127) * 65536];
  float w2 = pw[(size_t)((m0 - 1) & 127) * 65536];
  for (int m = m0; m < m0 + 64; ++m) {
    const float s3 = ps[(size_t)m * 65536];
    const float w3 = pw[(size_t)m * 65536];
    po[(size_t)(2 * m) * 65536] = Y0(s0, s1, s2, s3, w0, w1, w2, w3);
    po[(size_t)(2 * m + 1) * 65536] = Y1(s0, s1, s2, s3, w0, w1, w2, w3);
    s0 = s1; s1 = s2; s2 = s3;
    w0 = w1; w1 = w2; w2 = w3;
  }
}

__global__ __launch_bounds__(256) void wav_axis2(float* __restrict__ buf,
                                                 const float* __restrict__ h) {
  __shared__ float tile[256][32];
  const int t = threadIdx.x;
  const int c = t & 31;
  const int g = t >> 5;
  const size_t slice = (size_t)(blockIdx.x >> 3);
  const int col0 = (blockIdx.x & 7) * 32;
  float* __restrict__ p = buf + slice * 65536 + col0;
#pragma unroll
  for (int i = 0; i < 32; ++i) {
    const int rr = i * 8 + g;
    tile[rr][c] = p[rr * 256 + c];
  }
  __syncthreads();
  FILT_DECL(h)
  const int m0 = g * 16;
  float s0 = tile[(m0 - 3) & 127][c];
  float s1 = tile[(m0 - 2) & 127][c];
  float s2 = tile[(m0 - 1) & 127][c];
  float w0 = tile[128 + ((m0 - 3) & 127)][c];
  float w1 = tile[128 + ((m0 - 2) & 127)][c];
  float w2 = tile[128 + ((m0 - 1) & 127)][c];
#pragma unroll
  for (int m = m0; m < m0 + 16; ++m) {
    const float s3 = tile[m][c];
    const float w3 = tile[128 + m][c];
    p[(2 * m) * 256 + c] = Y0(s0, s1, s2, s3, w0, w1, w2, w3);
    p[(2 * m + 1) * 256 + c] = Y1(s0, s1, s2, s3, w0, w1, w2, w3);
    s0 = s1; s1 = s2; s2 = s3;
    w0 = w1; w1 = w2; w2 = w3;
  }
}

__global__ __launch_bounds__(256) void wav_axis3(float* __restrict__ buf,
                                                 const float* __restrict__ h) {
  __shared__ float tile[512];
  const int t = threadIdx.x;
  float* __restrict__ p = buf + (size_t)blockIdx.x * 512;
  tile[t] = p[t];
  tile[256 + t] = p[256 + t];
  __syncthreads();
  FILT_DECL(h)
  const int rr = t >> 7;
  const int m = t & 127;
  const float* __restrict__ line = tile + rr * 256;
  const float s0 = line[(m - 3) & 127];
  const float s1 = line[(m - 2) & 127];
  const float s2 = line[(m - 1) & 127];
  const float s3 = line[m];
  const float w0 = line[128 + ((m - 3) & 127)];
  const float w1 = line[128 + ((m - 2) & 127)];
  const float w2 = line[128 + ((m - 1) & 127)];
  const float w3 = line[128 + m];
  float2 y;
  y.x = Y0(s0, s1, s2, s3, w0, w1, w2, w3);
  y.y = Y1(s0, s1, s2, s3, w0, w1, w2, w3);
  *reinterpret_cast<float2*>(p + rr * 256 + 2 * m) = y;
}

extern "C" void kernel_launch(void* const* d_in, const int* in_sizes, int n_in,
                              void* d_out, int out_size, void* d_ws, size_t ws_size,
                              hipStream_t stream) {
  const float* x = (const float*)d_in[0];
  const float* h = (const float*)d_in[1];
  float* out = (float*)d_out;
  const size_t need = (size_t)4 * 256 * 256 * 256 * 4;   // 268 MB intermediate

  if (ws_size >= need) {
    float* tmp = (float*)d_ws;
    wav_a13<<<dim3(256, 2, 4), 256, 0, stream>>>(x, tmp, h);
    wav_b2<<<dim3(1024, 2), 256, 0, stream>>>(tmp, out, h);
  } else {
    wav_axis1<<<dim3(256, 2, 4), 256, 0, stream>>>(x, out, h);
    wav_axis2<<<dim3(8192), 256, 0, stream>>>(out, h);
    wav_axis3<<<dim3(131072), 256, 0, stream>>>(out, h);
  }
}

// Round 19
// 220.573 us; speedup vs baseline: 1.1168x; 1.0273x over previous
//
#include <hip/hip_runtime.h>

// Inverse 3D DWT (DB4, periodization), (4,256,256,256) fp32.  [R13 champion]
// pass 1: axis-1 streaming transform, x -> ws (scalar, dense-row grid, NT loads;
//         measured ~6.1 TB/s, at roofline)
// pass 2: fused axis-2 + axis-3, tile 16 (d2) x 256 (d3), 256 threads,
//         22x264 LDS (23.2 KB -> 7 blocks/CU).
//         Staging: global_load_lds, i2=k (literal), c=t (fixed) -> 1 add/iter.
//         axis-2: one thread per column (8 pairs, no cross-lane hazard).
//         halo LDS layout for aligned axis-3 vector reads; pk_fma throughout.
// Polyphase: y[2m]   = sum_j s[(m+j-3)&127]*a[j] + w[..]*c[j]
//            y[2m+1] = sum_j s[(m+j-3)&127]*b[j] + w[..]*d[j]
// a[j]=h[6-2j], b[j]=h[7-2j], c[j]=h[2j+1], d[j]=-h[2j].
// NOTE: FILT_DECL owns a0..a3,b0..b3,c0..c3,d0..d3 — don't shadow.

typedef float f32x2 __attribute__((ext_vector_type(2)));

#define FILT_DECL(h)                                          \
  const float a0 = h[6], a1 = h[4], a2 = h[2], a3 = h[0];     \
  const float b0 = h[7], b1 = h[5], b2 = h[3], b3 = h[1];     \
  const float c0 = h[1], c1 = h[3], c2 = h[5], c3 = h[7];     \
  const float d0 = -h[0], d1 = -h[2], d2 = -h[4], d3 = -h[6];

#define Y0(s0,s1,s2,s3,w0,w1,w2,w3)                                        \
  fmaf(w3, c3, fmaf(w2, c2, fmaf(w1, c1, fmaf(w0, c0,                      \
  fmaf(s3, a3, fmaf(s2, a2, fmaf(s1, a1, s0 * a0)))))))
#define Y1(s0,s1,s2,s3,w0,w1,w2,w3)                                        \
  fmaf(w3, d3, fmaf(w2, d2, fmaf(w1, d1, fmaf(w0, d0,                      \
  fmaf(s3, b3, fmaf(s2, b2, fmaf(s1, b1, s0 * b0)))))))

// packed fma: acc.xy += splat(s) * k.xy   (lowers to v_pk_fma_f32)
#define PKFMA(s, k, acc) __builtin_elementwise_fma((f32x2){(s),(s)}, (k), (acc))

// global -> LDS direct DMA, 4 bytes per lane
__device__ __forceinline__ void gload_lds4(const float* g, float* l) {
  auto gp = reinterpret_cast<const __attribute__((address_space(1))) int*>(
      reinterpret_cast<uintptr_t>(g));
  auto lp = reinterpret_cast<__attribute__((address_space(3))) int*>(
      reinterpret_cast<uintptr_t>(l));
  __builtin_amdgcn_global_load_lds(gp, lp, 4, 0, 0);
}

// ---------------- pass 1: axis 1 (row stride 65536), scalar, in -> tmp ----
__global__ __launch_bounds__(256) void wav_axis1_s(const float* __restrict__ in,
                                                   float* __restrict__ tmp,
                                                   const float* __restrict__ h) {
  const int inner = blockIdx.x * 256 + threadIdx.x;
  const int m0 = blockIdx.y * 64;
  const size_t base = (size_t)blockIdx.z * (256u * 65536u) + (unsigned)inner;
  const float* __restrict__ ps = in + base;
  const float* __restrict__ pw = in + base + (size_t)128 * 65536;
  float* __restrict__ po = tmp + base;
  FILT_DECL(h)
  float s0 = __builtin_nontemporal_load(&ps[(size_t)((m0 - 3) & 127) * 65536]);
  float s1 = __builtin_nontemporal_load(&ps[(size_t)((m0 - 2) & 127) * 65536]);
  float s2 = __builtin_nontemporal_load(&ps[(size_t)((m0 - 1) & 127) * 65536]);
  float w0 = __builtin_nontemporal_load(&pw[(size_t)((m0 - 3) & 127) * 65536]);
  float w1 = __builtin_nontemporal_load(&pw[(size_t)((m0 - 2) & 127) * 65536]);
  float w2 = __builtin_nontemporal_load(&pw[(size_t)((m0 - 1) & 127) * 65536]);
  for (int m = m0; m < m0 + 64; ++m) {
    const float s3 = __builtin_nontemporal_load(&ps[(size_t)m * 65536]);
    const float w3 = __builtin_nontemporal_load(&pw[(size_t)m * 65536]);
    po[(size_t)(2 * m) * 65536] = Y0(s0, s1, s2, s3, w0, w1, w2, w3);
    po[(size_t)(2 * m + 1) * 65536] = Y1(s0, s1, s2, s3, w0, w1, w2, w3);
    s0 = s1; s1 = s2; s2 = s3;
    w0 = w1; w1 = w2; w2 = w3;
  }
}

// ---------------- pass 2: fused axes 2+3, 16-row tile ---------------------
// LDS rows 0..10 = s (11 = 8 pairs + 3 halo), 11..21 = w.
// cols: [s-halo 0..2 | s 3..130 | pad | w-halo 132..134 | w 135..262]
#define LSTR 264
__global__ __launch_bounds__(256, 7) void wav_t23s(const float* __restrict__ tmp,
                                                   float* __restrict__ out,
                                                   const float* __restrict__ hg) {
  __shared__ __align__(16) float lb[22 * LSTR];  // 23.2 KB -> 7 blocks/CU
  const int t = threadIdx.x;
  const int d2t = blockIdx.x;                    // 0..15 (16 d2-rows each)
  const size_t slice = blockIdx.y;               // b*256 + d1
  const float* __restrict__ src = tmp + slice * 65536;
  FILT_DECL(hg)
  const f32x2 AB0 = {a0, b0}, AB1 = {a1, b1}, AB2 = {a2, b2}, AB3 = {a3, b3};
  const f32x2 CD0 = {c0, d0}, CD1 = {c1, d1}, CD2 = {c2, d2}, CD3 = {c3, d3};
  const int mb2 = 8 * d2t - 3;

  // stage 22 rows x 256 cols; c = t (fixed), i2 = k (literal) -> addr math
  // is one 64-bit add per row. Wave window never crosses the c=128 seam.
  {
    const int phys = t + ((t < 128) ? 3 : 7);
#pragma unroll
    for (int k = 0; k < 11; ++k) {               // s rows
      const int g2 = (mb2 + k) & 127;
      gload_lds4(src + (g2 << 8) + t, &lb[k * LSTR + phys]);
    }
#pragma unroll
    for (int k = 0; k < 11; ++k) {               // w rows
      const int g2 = 128 + ((mb2 + k) & 127);
      gload_lds4(src + (g2 << 8) + t, &lb[(11 + k) * LSTR + phys]);
    }
  }
  __syncthreads();

  // axis-2: one thread per column j=t; 8 pairs. Dead-slot in place:
  // pair p reads s rows p..p+3 / w rows p..p+3, writes y0->row p, y1->row 11+p.
  // Entire column owned by one thread -> no cross-lane hazard.
  {
    const int pj = t + ((t < 128) ? 3 : 7);
    float S[11], W[11];
#pragma unroll
    for (int i = 0; i < 11; ++i) S[i] = lb[i * LSTR + pj];
#pragma unroll
    for (int i = 0; i < 11; ++i) W[i] = lb[(11 + i) * LSTR + pj];
    // transformed cols 125..127 / 253..255 duplicated into halos
    const int hcol = (t >= 125 && t < 128) ? (t - 125)
                   : ((t >= 253) ? (t - 121) : -1);
#pragma unroll
    for (int q = 0; q < 8; ++q) {
      f32x2 acc = (f32x2){S[q], S[q]} * AB0;
      acc = PKFMA(S[q+1], AB1, acc);
      acc = PKFMA(S[q+2], AB2, acc);
      acc = PKFMA(S[q+3], AB3, acc);
      acc = PKFMA(W[q],   CD0, acc);
      acc = PKFMA(W[q+1], CD1, acc);
      acc = PKFMA(W[q+2], CD2, acc);
      acc = PKFMA(W[q+3], CD3, acc);
      lb[q * LSTR + pj] = acc.x;
      lb[(11 + q) * LSTR + pj] = acc.y;
      if (hcol >= 0) {
        lb[q * LSTR + hcol] = acc.x;
        lb[(11 + q) * LSTR + hcol] = acc.y;
      }
    }
  }
  __syncthreads();

  // axis-3: r = t>>4 (0..15 local d2 row), 8 pairs starting m0 = 8*(t&15).
  // Local row r -> phys row (r&1 ? 11+(r>>1) : r>>1). Halo layout ->
  // contiguous aligned reads: S[i]=lb[prow+m0+i], W[i]=lb[prow+132+m0+i].
  const int r = t >> 4, m0 = (t & 15) * 8;
  const int prow = ((r & 1) ? (11 + (r >> 1)) : (r >> 1)) * LSTR;
  float S[11], W[11];
  {
    const float4 sa = *reinterpret_cast<const float4*>(&lb[prow + m0]);
    const float4 sb = *reinterpret_cast<const float4*>(&lb[prow + m0 + 4]);
    const float2 sc = *reinterpret_cast<const float2*>(&lb[prow + m0 + 8]);
    S[0]=sa.x; S[1]=sa.y; S[2]=sa.z; S[3]=sa.w;
    S[4]=sb.x; S[5]=sb.y; S[6]=sb.z; S[7]=sb.w;
    S[8]=sc.x; S[9]=sc.y; S[10]=lb[prow + m0 + 10];
    const float4 wa = *reinterpret_cast<const float4*>(&lb[prow + 132 + m0]);
    const float4 wb = *reinterpret_cast<const float4*>(&lb[prow + 132 + m0 + 4]);
    const float2 wc = *reinterpret_cast<const float2*>(&lb[prow + 132 + m0 + 8]);
    W[0]=wa.x; W[1]=wa.y; W[2]=wa.z; W[3]=wa.w;
    W[4]=wb.x; W[5]=wb.y; W[6]=wb.z; W[7]=wb.w;
    W[8]=wc.x; W[9]=wc.y; W[10]=lb[prow + 132 + m0 + 10];
  }
  float* __restrict__ dst = out + slice * 65536
      + (size_t)(16 * d2t + r) * 256 + 16 * (t & 15);
#pragma unroll
  for (int g = 0; g < 4; ++g) {
    f32x2 eA = (f32x2){S[2*g], S[2*g]} * AB0;
    eA = PKFMA(S[2*g+1], AB1, eA);
    eA = PKFMA(S[2*g+2], AB2, eA);
    eA = PKFMA(S[2*g+3], AB3, eA);
    eA = PKFMA(W[2*g],   CD0, eA);
    eA = PKFMA(W[2*g+1], CD1, eA);
    eA = PKFMA(W[2*g+2], CD2, eA);
    eA = PKFMA(W[2*g+3], CD3, eA);
    f32x2 eB = (f32x2){S[2*g+1], S[2*g+1]} * AB0;
    eB = PKFMA(S[2*g+2], AB1, eB);
    eB = PKFMA(S[2*g+3], AB2, eB);
    eB = PKFMA(S[2*g+4], AB3, eB);
    eB = PKFMA(W[2*g+1], CD0, eB);
    eB = PKFMA(W[2*g+2], CD1, eB);
    eB = PKFMA(W[2*g+3], CD2, eB);
    eB = PKFMA(W[2*g+4], CD3, eB);
    *reinterpret_cast<float4*>(dst + 4 * g) = make_float4(eA.x, eA.y, eB.x, eB.y);
  }
}

// ================= fallback 3-pass (verified round 2) =================
__global__ __launch_bounds__(256) void wav_axis1(const float* __restrict__ in,
                                                 float* __restrict__ out,
                                                 const float* __restrict__ h) {
  const int inner = blockIdx.x * 256 + threadIdx.x;
  const int m0 = blockIdx.y * 64;
  const size_t base = (size_t)blockIdx.z * (256u * 65536u) + (unsigned)inner;
  const float* __restrict__ ps = in + base;
  const float* __restrict__ pw = in + base + (size_t)128 * 65536;
  float* __restrict__ po = out + base;
  FILT_DECL(h)
  float s0 = ps[(size_t)((m0 - 3) & 127) * 65536];
  float s1 = ps[(size_t)((m0 - 2) & 127) * 65536];
  float s2 = ps[(size_t)((m0 - 1) & 127) * 65536];
  float w0 = pw[(size_t)((m0 - 3) & 127) * 65536];
  float w1 = pw[(size_t)((m0 - 2) & 127) * 65536];
  float w2 = pw[(size_t)((m0 - 1) & 127) * 65536];
  for (int m = m0; m < m0 + 64; ++m) {
    const float s3 = ps[(size_t)m * 65536];
    const float w3 = pw[(size_t)m * 65536];
    po[(size_t)(2 * m) * 65536] = Y0(s0, s1, s2, s3, w0, w1, w2, w3);
    po[(size_t)(2 * m + 1) * 65536] = Y1(s0, s1, s2, s3, w0, w1, w2, w3);
    s0 = s1; s1 = s2; s2 = s3;
    w0 = w1; w1 = w2; w2 = w3;
  }
}

__global__ __launch_bounds__(256) void wav_axis2(float* __restrict__ buf,
                                                 const float* __restrict__ h) {
  __shared__ float tile[256][32];
  const int t = threadIdx.x;
  const int c = t & 31;
  const int g = t >> 5;
  const size_t slice = (size_t)(blockIdx.x >> 3);
  const int col0 = (blockIdx.x & 7) * 32;
  float* __restrict__ p = buf + slice * 65536 + col0;
#pragma unroll
  for (int i = 0; i < 32; ++i) {
    const int rr = i * 8 + g;
    tile[rr][c] = p[rr * 256 + c];
  }
  __syncthreads();
  FILT_DECL(h)
  const int m0 = g * 16;
  float s0 = tile[(m0 - 3) & 127][c];
  float s1 = tile[(m0 - 2) & 127][c];
  float s2 = tile[(m0 - 1) & 127][c];
  float w0 = tile[128 + ((m0 - 3) & 127)][c];
  float w1 = tile[128 + ((m0 - 2) & 127)][c];
  float w2 = tile[128 + ((m0 - 1) & 127)][c];
#pragma unroll
  for (int m = m0; m < m0 + 16; ++m) {
    const float s3 = tile[m][c];
    const float w3 = tile[128 + m][c];
    p[(2 * m) * 256 + c] = Y0(s0, s1, s2, s3, w0, w1, w2, w3);
    p[(2 * m + 1) * 256 + c] = Y1(s0, s1, s2, s3, w0, w1, w2, w3);
    s0 = s1; s1 = s2; s2 = s3;
    w0 = w1; w1 = w2; w2 = w3;
  }
}

__global__ __launch_bounds__(256) void wav_axis3(float* __restrict__ buf,
                                                 const float* __restrict__ h) {
  __shared__ float tile[512];
  const int t = threadIdx.x;
  float* __restrict__ p = buf + (size_t)blockIdx.x * 512;
  tile[t] = p[t];
  tile[256 + t] = p[256 + t];
  __syncthreads();
  FILT_DECL(h)
  const int rr = t >> 7;
  const int m = t & 127;
  const float* __restrict__ line = tile + rr * 256;
  const float s0 = line[(m - 3) & 127];
  const float s1 = line[(m - 2) & 127];
  const float s2 = line[(m - 1) & 127];
  const float s3 = line[m];
  const float w0 = line[128 + ((m - 3) & 127)];
  const float w1 = line[128 + ((m - 2) & 127)];
  const float w2 = line[128 + ((m - 1) & 127)];
  const float w3 = line[128 + m];
  float2 y;
  y.x = Y0(s0, s1, s2, s3, w0, w1, w2, w3);
  y.y = Y1(s0, s1, s2, s3, w0, w1, w2, w3);
  *reinterpret_cast<float2*>(p + rr * 256 + 2 * m) = y;
}

extern "C" void kernel_launch(void* const* d_in, const int* in_sizes, int n_in,
                              void* d_out, int out_size, void* d_ws, size_t ws_size,
                              hipStream_t stream) {
  const float* x = (const float*)d_in[0];
  const float* h = (const float*)d_in[1];
  float* out = (float*)d_out;
  const size_t need = (size_t)4 * 256 * 256 * 256 * 4;   // 268 MB intermediate

  if (ws_size >= need) {
    float* tmp = (float*)d_ws;
    wav_axis1_s<<<dim3(256, 2, 4), 256, 0, stream>>>(x, tmp, h);
    wav_t23s<<<dim3(16, 1024), 256, 0, stream>>>(tmp, out, h);
  } else {
    wav_axis1<<<dim3(256, 2, 4), 256, 0, stream>>>(x, out, h);
    wav_axis2<<<dim3(8192), 256, 0, stream>>>(out, h);
    wav_axis3<<<dim3(131072), 256, 0, stream>>>(out, h);
  }
}